// Round 11
// baseline (782.985 us; speedup 1.0000x reference)
//
#include <hip/hip_runtime.h>
#include <math.h>

#define S_ 2048
#define N_ 256
#define MID_ 512
#define NB_ 4
#define JSL_ 128  // MID_/NB_
#define LN_EPS_ 1e-5f
#define NBLK_ 64          // blocks launched for the election
#define NSTEP_ 253        // fast-path steps (t = 3..255)
#define BSTRIDE_ 288      // floats per role payload (256 + 2 stats + pad; 9 x 128B lines)
#define SLOT_F_ (NB_*BSTRIDE_)   // floats per step slot
#define TAGW_ 32          // ints per step tag line (128 B; NB_ tag dwords packed per step)

typedef float f32x4 __attribute__((ext_vector_type(4)));
typedef float f32x2 __attribute__((ext_vector_type(2)));

__device__ __forceinline__ float gelu_exact(float x){
    return 0.5f * x * (1.0f + erff(x * 0.70710678118654752440f));
}

// RMW read at the coherence point (r5/r6/r9/r10-proven): stale-proof, hang-proof
__device__ __forceinline__ int atomic_read_l2(int* p){
    int v; int zero = 0;
    asm volatile("global_atomic_add %0, %1, %2, off sc0\n\ts_waitcnt vmcnt(0)"
                 : "=v"(v) : "v"(p), "v"(zero) : "memory");
    return v;
}

// ---------------- setup kernels ----------------

__global__ void k_init(const float* __restrict__ xs, const float* __restrict__ w2,
                       float* __restrict__ probs, float* __restrict__ w2T,
                       unsigned int* __restrict__ wmask32, int* __restrict__ tagsall)
{
    int idx = blockIdx.x * blockDim.x + threadIdx.x;   // grid covers 524288
    if (idx < S_*N_) probs[idx] = xs[idx];
    if (idx < MID_*N_) {
        int j = idx / N_, c = idx % N_;
        w2T[c*MID_ + j] = w2[idx];
    }
    if (idx < (N_*N_)/4) wmask32[idx] = 0u;
    if (idx < NSTEP_*TAGW_ + 8) tagsall[idx] = 0;      // tags + xcd cnt
    if (idx == 0) tagsall[NSTEP_*TAGW_ + 8] = -1;      // winner
}

__global__ void k_mask(const int* __restrict__ ids, unsigned char* __restrict__ wmask){
    int i = blockIdx.x*blockDim.x + threadIdx.x;       // 524288 = S_*N_
    if (i < S_*N_){
        int t = i & (N_-1);        // i = k*256 + t  (row-major ids_ary[k][t])
        int c = ids[i];
        wmask[t*N_ + c] = 1;       // benign write race, value always 1
    }
}

// pack byte-mask into bit-mask: wmaskb[t*8 + c/32] bit (c%32)
__global__ void k_pack(const unsigned char* __restrict__ wmask,
                       unsigned int* __restrict__ wmaskb){
    int d = blockIdx.x*blockDim.x + threadIdx.x;       // 2048 total
    if (d < (N_*N_)/32){
        const unsigned int* p = (const unsigned int*)(wmask + d*32);
        unsigned int bits = 0;
        #pragma unroll
        for (int k = 0; k < 8; k++){
            unsigned int v = p[k];
            if (v & 0x000000FFu) bits |= 1u << (k*4 + 0);
            if (v & 0x0000FF00u) bits |= 1u << (k*4 + 1);
            if (v & 0x00FF0000u) bits |= 1u << (k*4 + 2);
            if (v & 0xFF000000u) bits |= 1u << (k*4 + 3);
        }
        wmaskb[d] = bits;
    }
}

__global__ void k_ab(const float* __restrict__ gamma, const float* __restrict__ beta,
                     const float* __restrict__ w2, const float* __restrict__ b2,
                     float* __restrict__ A, float* __restrict__ Bc){
    __shared__ float ra[256], rb[256];
    int c = blockIdx.x, tid = threadIdx.x;
    float a = 0.f, b = 0.f;
    for (int j = tid; j < MID_; j += 256){
        float v = w2[j*N_ + c];
        a += gamma[j]*v;
        b += beta[j]*v;
    }
    ra[tid] = a; rb[tid] = b; __syncthreads();
    for (int off = 128; off > 0; off >>= 1){
        if (tid < off){ ra[tid] += ra[tid+off]; rb[tid] += rb[tid+off]; }
        __syncthreads();
    }
    if (tid == 0){ A[c] = ra[0]; Bc[c] = rb[0] + b2[c]; }
}

// ---------------- exact full-row step (t = 0..2) ----------------

__global__ __launch_bounds__(256) void k_full_rows(
    const float* __restrict__ probs, const float* __restrict__ w1,
    const float* __restrict__ b1, const float* __restrict__ gamma,
    const float* __restrict__ beta, const float* __restrict__ w2T,
    const float* __restrict__ b2, const int* __restrict__ ids,
    float* __restrict__ ps, int t)
{
    __shared__ float prow[8][N_];
    int tid = threadIdx.x;
    int r0 = blockIdx.x * 8;
    for (int i = tid; i < 8*N_; i += 256)
        prow[i>>8][i&255] = probs[(r0 + (i>>8))*N_ + (i&255)];
    __syncthreads();
    int r = tid >> 5, jg = tid & 31;      // 8 rows x 32 threads
    float h[16];
    #pragma unroll
    for (int m = 0; m < 16; m++) h[m] = b1[jg + 32*m];
    for (int c = 0; c < N_; c++){
        float p = prow[r][c];
        const float* w1r = w1 + c*MID_;
        #pragma unroll
        for (int m = 0; m < 16; m++) h[m] = fmaf(p, w1r[jg + 32*m], h[m]);
    }
    float s1 = 0.f, s2 = 0.f;
    #pragma unroll
    for (int m = 0; m < 16; m++){
        float g = gelu_exact(h[m]);
        h[m] = g; s1 += g; s2 += g*g;
    }
    #pragma unroll
    for (int off = 16; off > 0; off >>= 1){
        s1 += __shfl_xor(s1, off, 32);
        s2 += __shfl_xor(s2, off, 32);
    }
    float mu  = s1 * (1.f/MID_);
    float var = s2 * (1.f/MID_) - mu*mu;
    float inv = rsqrtf(var + LN_EPS_);
    int rg = r0 + r;
    int id = ids[rg*N_ + t];
    const float* wrow = w2T + id*MID_;
    float acc = 0.f;
    #pragma unroll
    for (int m = 0; m < 16; m++){
        int j = jg + 32*m;
        float hn = (h[m] - mu)*inv*gamma[j] + beta[j];
        acc = fmaf(hn, wrow[j], acc);
    }
    #pragma unroll
    for (int off = 16; off > 0; off >>= 1) acc += __shfl_xor(acc, off, 32);
    if (jg == 0) ps[rg] = 1.f/(1.f + expf(-(acc + b2[id])));
}

// last-k-wins scatter (numpy fancy-assignment semantics)
__global__ void k_scatter(const int* __restrict__ ids, const float* __restrict__ ps,
                          float* __restrict__ newval, int* __restrict__ wrote, int t){
    __shared__ int lastk[N_];
    int tid = threadIdx.x;
    lastk[tid] = -1;
    __syncthreads();
    for (int k = tid; k < S_; k += 256) atomicMax(&lastk[ids[k*N_ + t]], k);
    __syncthreads();
    int lk = lastk[tid];
    wrote[tid] = (lk >= 0) ? 1 : 0;
    if (lk >= 0) newval[tid] = ps[lk];
}

__global__ void k_apply(float* __restrict__ probs, const float* __restrict__ newval,
                        const int* __restrict__ wrote){
    int idx = blockIdx.x*blockDim.x + threadIdx.x;     // 524288
    int c = idx & (N_-1);
    if (wrote[c]) probs[idx] = newval[c];
}

// ---------------- persistent single-row fast path (t = 3..255) ----------------
// r10-proven structure (same-XCD team, register weights, never-reused slots,
// block drain before tag publish, parallel RMW tag polls). Delta this round:
// NB_ = 4 (team of 4 blocks, each owning 128 j's) -- halves exchange
// participants (skew, poll contention, P4 traffic) at the cost of doubling
// the (cheap) per-thread register compute: 64 w1 + 64 gamma*w2 floats,
// statically indexed / fully unrolled.

__global__ __launch_bounds__(512) void k_fast(
    const float* __restrict__ w1, const float* __restrict__ b1,
    const float* __restrict__ gamma, const float* __restrict__ w2,
    const float* __restrict__ A, const float* __restrict__ Bc,
    const unsigned int* __restrict__ wmaskb, const float* __restrict__ probs,
    float* __restrict__ slots, int* __restrict__ tags,
    int* __restrict__ cnt, int* __restrict__ winner,
    float* __restrict__ commonFinal, int t0)
{
    __shared__ int s_role;
    __shared__ __attribute__((aligned(16))) float commonS[N_];  // col-swizzled
    __shared__ __attribute__((aligned(16))) float gvals[JSL_];
    __shared__ float ws8[16];            // per-wave LN-stat partials
    __shared__ float pst[NB_][2];        // imported stats
    __shared__ unsigned int wbits[(N_*N_)/32];  // 8 KiB bit-mask

    int tid = threadIdx.x;

    // ---- election: RMW-only, hang-proof (r5/r9/r10-proven) ----
    if (tid == 0){
        int xcd;
        asm volatile("s_getreg_b32 %0, hwreg(HW_REG_XCC_ID)" : "=s"(xcd));
        xcd &= 7;
        int pos = atomicAdd(&cnt[xcd], 1);
        int role = -1;
        if (pos == NB_ - 1){                       // 4th block on this XCD
            int old = atomicCAS(winner, -1, xcd);
            if (old == -1) role = NB_ - 1;
        } else if (pos < NB_ - 1){
            int w;
            while ((w = atomicCAS(winner, -2, -2)) == -1)
                __builtin_amdgcn_s_sleep(2);
            if (w == xcd) role = pos;
        }
        s_role = role;
    }
    __syncthreads();
    int role = s_role;
    if (role < 0) return;
    int j0 = role * JSL_;

    int l = tid & 63, w = tid >> 6;
    int cq = l & 3;                      // Phase A c-quarter: c in [cq*64, cq*64+64)
    int jA = (w<<4) + (l>>2);            // Phase A block-local j in [0,128)
    int cB = w*32 + (l & 31);            // Phase B output column
    int khalf = l >> 5;                  // Phase B k-half (0/1), 64 k each

    // ---- stage weights into REGISTERS (statically indexed, fully unrolled) ----
    float w1r[64];
    #pragma unroll
    for (int cc = 0; cc < 64; cc++)
        w1r[cc] = w1[(cq*64 + cc)*MID_ + j0 + jA];
    float g2r[64];
    #pragma unroll
    for (int kk = 0; kk < 64; kk++)
        g2r[kk] = gamma[j0 + khalf*64 + kk] * w2[(j0 + khalf*64 + kk)*N_ + cB];
    float b1v = b1[j0 + jA];

    for (int i = tid; i < (N_*N_)/32; i += 512) wbits[i] = wmaskb[i];
    if (tid < N_) commonS[tid ^ (((tid>>5)&7)<<2)] = probs[tid];  // rows identical
    float Ac  = (tid < N_) ? A[tid]  : 0.f;
    float Bcc = (tid < N_) ? Bc[tid] : 0.f;
    __syncthreads();

    for (int t = t0; t < N_; t++){
        int si = t - t0;
        float* slot = slots + si*SLOT_F_;          // fresh slot every step
        float* myp  = slot + role*BSTRIDE_;
        // Phase A (all 8 waves): h partials from register w1 + broadcast commonS
        {
            float a0=0.f, a1=0.f, a2=0.f, a3=0.f;
            #pragma unroll
            for (int cc = 0; cc < 16; cc++){
                int c = cq*64 + cc*4;
                int base = c ^ (((c>>5)&7)<<2);    // 4 cq -> 4 distinct bank quads
                f32x4 cv = *(const f32x4*)(&commonS[base]);
                a0 = fmaf(w1r[cc*4+0], cv.x, a0);
                a1 = fmaf(w1r[cc*4+1], cv.y, a1);
                a2 = fmaf(w1r[cc*4+2], cv.z, a2);
                a3 = fmaf(w1r[cc*4+3], cv.w, a3);
            }
            float hp = (a0+a1) + (a2+a3);
            hp += __shfl_xor(hp, 1);     // reduce over cq (lane bits 0-1)
            hp += __shfl_xor(hp, 2);
            float g = gelu_exact(hp + b1v);
            float s1 = g, s2 = g*g;
            s1 += __shfl_xor(s1, 4);  s2 += __shfl_xor(s2, 4);   // over j (bits 2-5)
            s1 += __shfl_xor(s1, 8);  s2 += __shfl_xor(s2, 8);
            s1 += __shfl_xor(s1, 16); s2 += __shfl_xor(s2, 16);
            s1 += __shfl_xor(s1, 32); s2 += __shfl_xor(s2, 32);
            if (l == 0){ ws8[w*2] = s1; ws8[w*2+1] = s2; }
            if (cq == 0) gvals[jA] = g;
        }
        __syncthreads();                 // bar1: gvals/ws8 ready
        // Phase B (all 8 waves): partial matvec from register gw2 + broadcast gvals
        {
            float p0=0.f, p1=0.f, p2=0.f, p3=0.f;
            #pragma unroll
            for (int kk = 0; kk < 16; kk++){
                f32x4 gv = *(const f32x4*)(&gvals[khalf*64 + kk*4]);
                p0 = fmaf(g2r[kk*4+0], gv.x, p0);
                p1 = fmaf(g2r[kk*4+1], gv.y, p1);
                p2 = fmaf(g2r[kk*4+2], gv.z, p2);
                p3 = fmaf(g2r[kk*4+3], gv.w, p3);
            }
            float p = (p0+p1) + (p2+p3);
            p += __shfl_xor(p, 32);      // combine the two k-halves
            if (l < 32) myp[cB] = p;     // coalesced 128B per wave
        }
        if (tid == 0){
            float S1 = 0.f, S2 = 0.f;
            #pragma unroll
            for (int ww = 0; ww < 8; ww++){ S1 += ws8[ww*2]; S2 += ws8[ww*2+1]; }
            f32x2 st; st.x = S1; st.y = S2;
            *(f32x2*)(myp + 256) = st;
        }
        asm volatile("s_waitcnt vmcnt(0)" ::: "memory");  // own stores acked at L2
        __syncthreads();                 // bar2: ALL payload stores at L2
        // publish: one plain tag-dword store (tag line never plain-loaded)
        if (tid == 0)
            *(volatile int*)(tags + si*TAGW_ + role) = t + 1;
        // poll: NB_ parallel RMW polls (r5-proven primitive); import stats
        if (tid < NB_){
            int* tp = tags + si*TAGW_ + tid;
            while (atomic_read_l2(tp) < t + 1) {}
            f32x2 st = *(const f32x2*)(slot + tid*BSTRIDE_ + 256);
            pst[tid][0] = st.x; pst[tid][1] = st.y;
        }
        __syncthreads();                 // bar3: all tags confirmed, stats in LDS
        // P4: payload first-touch reads (all tags already confirmed), finish
        if (tid < N_){
            const float* sp = slot + tid;
            float s1 = 0.f;
            #pragma unroll
            for (int bb = 0; bb < NB_; bb++) s1 += sp[bb*BSTRIDE_];
            float S1 = 0.f, S2 = 0.f;
            #pragma unroll
            for (int bb = 0; bb < NB_; bb++){ S1 += pst[bb][0]; S2 += pst[bb][1]; }
            float mu  = S1 * (1.f/MID_);
            float var = S2 * (1.f/MID_) - mu*mu;
            float inv = rsqrtf(var + LN_EPS_);
            float s = inv*(s1 - mu*Ac) + Bcc;
            float o = 1.f/(1.f + expf(-s));
            if ((wbits[(t<<3) + (tid>>5)] >> (tid&31)) & 1u)
                commonS[tid ^ (((tid>>5)&7)<<2)] = o;
        }
        __syncthreads();                 // bar4: commonS updated
    }
    if (role == 0 && tid < N_)
        commonFinal[tid] = commonS[tid ^ (((tid>>5)&7)<<2)];
}

__global__ void k_out(const float* __restrict__ commonFinal, float* __restrict__ out){
    int idx = blockIdx.x*blockDim.x + threadIdx.x;     // 524288
    out[idx] = commonFinal[idx & (N_-1)];
}

// ---------------- launch ----------------

extern "C" void kernel_launch(void* const* d_in, const int* in_sizes, int n_in,
                              void* d_out, int out_size, void* d_ws, size_t ws_size,
                              hipStream_t stream)
{
    const float* xs    = (const float*)d_in[0];
    const int*   ids   = (const int*)  d_in[1];
    const float* w1    = (const float*)d_in[2];
    const float* b1    = (const float*)d_in[3];
    const float* gamma = (const float*)d_in[4];
    const float* beta  = (const float*)d_in[5];
    const float* w2    = (const float*)d_in[6];
    const float* b2    = (const float*)d_in[7];
    float* out = (float*)d_out;

    float* ws      = (float*)d_ws;
    float* probs   = ws;                     // 524288 f32
    // slots alias probs[2048:] + w2T (both dead during k_fast):
    float* slots   = ws + 2048;              // 253*1152 = 291456 f32, ends 293504
    float* w2T     = ws + 524288;            // 131072 (used only before k_fast)
    float* A       = ws + 786432;            // 256
    float* Bc      = ws + 786688;            // 256
    float* ps      = ws + 786944;            // 2048
    float* newval  = ws + 788992;            // 256
    int*   wrote   = (int*)(ws + 789248);    // 256
    unsigned char* wmask = (unsigned char*)(ws + 789504);   // 65536 B -> ends 805888
    unsigned int* wmaskb = (unsigned int*)(ws + 805888);    // 2048 -> ends 807936
    int*   tagsall = (int*)(ws + 807936);    // 253*32 tags + 8 cnt + 1 winner
    int*   tags    = tagsall;
    int*   cnt     = tagsall + NSTEP_*TAGW_;
    int*   winner  = cnt + 8;
    float* commonFinal = ws + 816064;        // 256 -> ends 816320 (~3.27 MB)

    k_init<<<2048, 256, 0, stream>>>(xs, w2, probs, w2T,
                                     (unsigned int*)wmask, tagsall);
    k_mask<<<2048, 256, 0, stream>>>(ids, wmask);
    k_ab<<<256, 256, 0, stream>>>(gamma, beta, w2, b2, A, Bc);
    k_pack<<<8, 256, 0, stream>>>(wmask, wmaskb);

    for (int t = 0; t < 3; t++){
        k_full_rows<<<256, 256, 0, stream>>>(probs, w1, b1, gamma, beta, w2T, b2,
                                             ids, ps, t);
        k_scatter<<<1, 256, 0, stream>>>(ids, ps, newval, wrote, t);
        k_apply<<<2048, 256, 0, stream>>>(probs, newval, wrote);
    }

    k_fast<<<NBLK_, 512, 0, stream>>>(w1, b1, gamma, w2, A, Bc, wmaskb, probs,
                                      slots, tags, cnt, winner, commonFinal, 3);
    k_out<<<2048, 256, 0, stream>>>(commonFinal, out);
}

// Round 12
// 723.244 us; speedup vs baseline: 1.0826x; 1.0826x over previous
//
#include <hip/hip_runtime.h>
#include <math.h>

#define S_ 2048
#define N_ 256
#define MID_ 512
#define NB_ 8
#define JSL_ 64   // MID_/NB_
#define LN_EPS_ 1e-5f
#define NBLK_ 64          // blocks launched for the election
#define NSTEP_ 253        // fast-path steps (t = 3..255)
#define BSTRIDE_ 288      // floats per role payload (256 + 2 stats + pad; 9 x 128B lines)
#define SLOT_F_ (NB_*BSTRIDE_)   // 2304 floats per step slot
#define TAGST_ 16         // u64 per step tag line (128 B each)
#define TAG_TARGET_ 0x0101010101010101ULL

typedef float f32x4 __attribute__((ext_vector_type(4)));
typedef float f32x2 __attribute__((ext_vector_type(2)));

__device__ __forceinline__ float gelu_exact(float x){
    return 0.5f * x * (1.0f + erff(x * 0.70710678118654752440f));
}

// ---------------- setup kernels ----------------

__global__ void k_init(const float* __restrict__ xs, const float* __restrict__ w2,
                       float* __restrict__ probs, float* __restrict__ w2T,
                       unsigned int* __restrict__ wmaskb, int* __restrict__ tagw32,
                       int* __restrict__ cnt, int* __restrict__ winner)
{
    int idx = blockIdx.x * blockDim.x + threadIdx.x;   // grid covers 524288
    if (idx < S_*N_) probs[idx] = xs[idx];
    if (idx < MID_*N_) {
        int j = idx / N_, c = idx % N_;
        w2T[c*MID_ + j] = w2[idx];
    }
    if (idx < (N_*N_)/32) wmaskb[idx] = 0u;
    if (idx < NSTEP_*TAGST_*2) tagw32[idx] = 0;        // tag words (as ints)
    if (idx < 8) cnt[idx] = 0;
    if (idx == 0) *winner = -1;
}

// build bit-mask directly: wmaskb[t*8 + c/32] |= 1<<(c%32)
__global__ void k_maskb(const int* __restrict__ ids, unsigned int* __restrict__ wmaskb){
    int i = blockIdx.x*blockDim.x + threadIdx.x;       // 524288 = S_*N_
    if (i < S_*N_){
        int t = i & (N_-1);        // i = k*256 + t  (row-major ids_ary[k][t])
        int c = ids[i];
        atomicOr(&wmaskb[(t<<3) + (c>>5)], 1u << (c&31));
    }
}

__global__ void k_ab(const float* __restrict__ gamma, const float* __restrict__ beta,
                     const float* __restrict__ w2, const float* __restrict__ b2,
                     float* __restrict__ A, float* __restrict__ Bc){
    __shared__ float ra[256], rb[256];
    int c = blockIdx.x, tid = threadIdx.x;
    float a = 0.f, b = 0.f;
    for (int j = tid; j < MID_; j += 256){
        float v = w2[j*N_ + c];
        a += gamma[j]*v;
        b += beta[j]*v;
    }
    ra[tid] = a; rb[tid] = b; __syncthreads();
    for (int off = 128; off > 0; off >>= 1){
        if (tid < off){ ra[tid] += ra[tid+off]; rb[tid] += rb[tid+off]; }
        __syncthreads();
    }
    if (tid == 0){ A[c] = ra[0]; Bc[c] = rb[0] + b2[c]; }
}

// ---------------- exact full-row step (t = 0..2) ----------------

__global__ __launch_bounds__(256) void k_full_rows(
    const float* __restrict__ probs, const float* __restrict__ w1,
    const float* __restrict__ b1, const float* __restrict__ gamma,
    const float* __restrict__ beta, const float* __restrict__ w2T,
    const float* __restrict__ b2, const int* __restrict__ ids,
    float* __restrict__ ps, int t)
{
    __shared__ float prow[8][N_];
    int tid = threadIdx.x;
    int r0 = blockIdx.x * 8;
    for (int i = tid; i < 8*N_; i += 256)
        prow[i>>8][i&255] = probs[(r0 + (i>>8))*N_ + (i&255)];
    __syncthreads();
    int r = tid >> 5, jg = tid & 31;      // 8 rows x 32 threads
    float h[16];
    #pragma unroll
    for (int m = 0; m < 16; m++) h[m] = b1[jg + 32*m];
    for (int c = 0; c < N_; c++){
        float p = prow[r][c];
        const float* w1r = w1 + c*MID_;
        #pragma unroll
        for (int m = 0; m < 16; m++) h[m] = fmaf(p, w1r[jg + 32*m], h[m]);
    }
    float s1 = 0.f, s2 = 0.f;
    #pragma unroll
    for (int m = 0; m < 16; m++){
        float g = gelu_exact(h[m]);
        h[m] = g; s1 += g; s2 += g*g;
    }
    #pragma unroll
    for (int off = 16; off > 0; off >>= 1){
        s1 += __shfl_xor(s1, off, 32);
        s2 += __shfl_xor(s2, off, 32);
    }
    float mu  = s1 * (1.f/MID_);
    float var = s2 * (1.f/MID_) - mu*mu;
    float inv = rsqrtf(var + LN_EPS_);
    int rg = r0 + r;
    int id = ids[rg*N_ + t];
    const float* wrow = w2T + id*MID_;
    float acc = 0.f;
    #pragma unroll
    for (int m = 0; m < 16; m++){
        int j = jg + 32*m;
        float hn = (h[m] - mu)*inv*gamma[j] + beta[j];
        acc = fmaf(hn, wrow[j], acc);
    }
    #pragma unroll
    for (int off = 16; off > 0; off >>= 1) acc += __shfl_xor(acc, off, 32);
    if (jg == 0) ps[rg] = 1.f/(1.f + expf(-(acc + b2[id])));
}

// last-k-wins scatter (numpy fancy-assignment semantics)
__global__ void k_scatter(const int* __restrict__ ids, const float* __restrict__ ps,
                          float* __restrict__ newval, int* __restrict__ wrote, int t){
    __shared__ int lastk[N_];
    int tid = threadIdx.x;
    lastk[tid] = -1;
    __syncthreads();
    for (int k = tid; k < S_; k += 256) atomicMax(&lastk[ids[k*N_ + t]], k);
    __syncthreads();
    int lk = lastk[tid];
    wrote[tid] = (lk >= 0) ? 1 : 0;
    if (lk >= 0) newval[tid] = ps[lk];
}

__global__ void k_apply(float* __restrict__ probs, const float* __restrict__ newval,
                        const int* __restrict__ wrote){
    int idx = blockIdx.x*blockDim.x + threadIdx.x;     // 524288
    int c = idx & (N_-1);
    if (wrote[c]) probs[idx] = newval[c];
}

// ---------------- persistent single-row fast path (t = 3..255) ----------------
// r10-proven structure (same-XCD team of 8, register weights, never-reused
// slots, block drain before publish). Delta this round: FAIR-ATOMIC exchange
// -- publish is atomicAdd(tagword, 1<<8*role) on ONE u64 per step (queues
// fairly with polls; no plain-store starvation under the RMW storm), and only
// ONE thread per block polls (8 pollers vs 64) with s_sleep backoff.

__global__ __launch_bounds__(512) void k_fast(
    const float* __restrict__ w1, const float* __restrict__ b1,
    const float* __restrict__ gamma, const float* __restrict__ w2,
    const float* __restrict__ A, const float* __restrict__ Bc,
    const unsigned int* __restrict__ wmaskb, const float* __restrict__ probs,
    const float* __restrict__ newval, const int* __restrict__ wrote,
    float* __restrict__ slots, unsigned long long* __restrict__ tagw,
    int* __restrict__ cnt, int* __restrict__ winner,
    float* __restrict__ commonFinal, int t0)
{
    __shared__ int s_role;
    __shared__ __attribute__((aligned(16))) float commonS[N_];  // col-swizzled
    __shared__ __attribute__((aligned(16))) float gvals[JSL_];
    __shared__ float ws8[16];            // per-wave LN-stat partials
    __shared__ float pst[NB_][2];        // imported stats
    __shared__ unsigned int wbits[(N_*N_)/32];  // 8 KiB bit-mask

    int tid = threadIdx.x;

    // ---- election: RMW-only, hang-proof (r5/r9/r10-proven) ----
    if (tid == 0){
        int xcd;
        asm volatile("s_getreg_b32 %0, hwreg(HW_REG_XCC_ID)" : "=s"(xcd));
        xcd &= 7;
        int pos = atomicAdd(&cnt[xcd], 1);
        int role = -1;
        if (pos == NB_ - 1){                       // 8th block on this XCD
            int old = atomicCAS(winner, -1, xcd);
            if (old == -1) role = NB_ - 1;
        } else if (pos < NB_ - 1){
            int w;
            while ((w = atomicCAS(winner, -2, -2)) == -1)
                __builtin_amdgcn_s_sleep(2);
            if (w == xcd) role = pos;
        }
        s_role = role;
    }
    __syncthreads();
    int role = s_role;
    if (role < 0) return;
    int j0 = role * JSL_;

    int l = tid & 63, w = tid >> 6;
    int cg = l & 7;                      // Phase A c-group: c in [cg*32, cg*32+32)
    int jA = (w<<3) + (l>>3);            // Phase A block-local j in [0,64)
    int cB = w*32 + (l & 31);            // Phase B output column
    int khalf = l >> 5;                  // Phase B k-half (0/1)

    // ---- stage weights into REGISTERS (statically indexed, fully unrolled) ----
    float w1r[32];
    #pragma unroll
    for (int cc = 0; cc < 32; cc++)
        w1r[cc] = w1[(cg*32 + cc)*MID_ + j0 + jA];
    float g2r[32];
    #pragma unroll
    for (int kk = 0; kk < 32; kk++)
        g2r[kk] = gamma[j0 + khalf*32 + kk] * w2[(j0 + khalf*32 + kk)*N_ + cB];
    float b1v = b1[j0 + jA];

    for (int i = tid; i < (N_*N_)/32; i += 512) wbits[i] = wmaskb[i];
    if (tid < N_)                                     // overlay of step-2 scatter
        commonS[tid ^ (((tid>>5)&7)<<2)] = wrote[tid] ? newval[tid] : probs[tid];
    float Ac  = (tid < N_) ? A[tid]  : 0.f;
    float Bcc = (tid < N_) ? Bc[tid] : 0.f;
    __syncthreads();

    for (int t = t0; t < N_; t++){
        int si = t - t0;
        float* slot = slots + si*SLOT_F_;          // fresh slot every step
        float* myp  = slot + role*BSTRIDE_;
        // Phase A (all 8 waves): h partials from register w1 + broadcast commonS
        {
            float a0=0.f, a1=0.f, a2=0.f, a3=0.f;
            #pragma unroll
            for (int cc = 0; cc < 8; cc++){
                f32x4 cv = *(const f32x4*)(&commonS[(cg*32 + cc*4) ^ (cg<<2)]);
                a0 = fmaf(w1r[cc*4+0], cv.x, a0);
                a1 = fmaf(w1r[cc*4+1], cv.y, a1);
                a2 = fmaf(w1r[cc*4+2], cv.z, a2);
                a3 = fmaf(w1r[cc*4+3], cv.w, a3);
            }
            float hp = (a0+a1) + (a2+a3);
            hp += __shfl_xor(hp, 1);     // reduce over cg (lane bits 0-2)
            hp += __shfl_xor(hp, 2);
            hp += __shfl_xor(hp, 4);
            float g = gelu_exact(hp + b1v);
            float s1 = g, s2 = g*g;
            s1 += __shfl_xor(s1, 8);  s2 += __shfl_xor(s2, 8);   // over j (bits 3-5)
            s1 += __shfl_xor(s1, 16); s2 += __shfl_xor(s2, 16);
            s1 += __shfl_xor(s1, 32); s2 += __shfl_xor(s2, 32);
            if (l == 0){ ws8[w*2] = s1; ws8[w*2+1] = s2; }
            if (cg == 0) gvals[jA] = g;
        }
        __syncthreads();                 // bar1: gvals/ws8 ready
        // Phase B (all 8 waves): partial matvec from register gw2 + broadcast gvals
        {
            float p0=0.f, p1=0.f, p2=0.f, p3=0.f;
            #pragma unroll
            for (int kk = 0; kk < 8; kk++){
                f32x4 gv = *(const f32x4*)(&gvals[khalf*32 + kk*4]);
                p0 = fmaf(g2r[kk*4+0], gv.x, p0);
                p1 = fmaf(g2r[kk*4+1], gv.y, p1);
                p2 = fmaf(g2r[kk*4+2], gv.z, p2);
                p3 = fmaf(g2r[kk*4+3], gv.w, p3);
            }
            float p = (p0+p1) + (p2+p3);
            p += __shfl_xor(p, 32);      // combine the two k-halves
            if (l < 32) myp[cB] = p;     // coalesced 128B per wave
        }
        if (tid == 0){
            float S1 = 0.f, S2 = 0.f;
            #pragma unroll
            for (int ww = 0; ww < 8; ww++){ S1 += ws8[ww*2]; S2 += ws8[ww*2+1]; }
            f32x2 st; st.x = S1; st.y = S2;
            *(f32x2*)(myp + 256) = st;
        }
        asm volatile("s_waitcnt vmcnt(0)" ::: "memory");  // own stores acked at L2
        __syncthreads();                 // bar2: ALL payload stores at L2
        // publish + poll: fair atomics on ONE u64 tag word per step
        if (tid == 0){
            unsigned long long* tp = tagw + si*TAGST_;
            atomicAdd(tp, 1ULL << (8*role));            // publish (RMW, fair queue)
            while (atomicAdd(tp, 0ULL) != TAG_TARGET_)  // single poller per block
                __builtin_amdgcn_s_sleep(1);
        }
        __syncthreads();                 // bar3: all 8 payloads at L2
        // import stats (first touch, after tag word complete)
        if (tid < NB_){
            f32x2 st = *(const f32x2*)(slot + tid*BSTRIDE_ + 256);
            pst[tid][0] = st.x; pst[tid][1] = st.y;
        }
        __syncthreads();                 // bar4: stats in LDS
        // P4: payload first-touch reads, finish
        if (tid < N_){
            const float* sp = slot + tid;
            float s1 = 0.f;
            #pragma unroll
            for (int bb = 0; bb < NB_; bb++) s1 += sp[bb*BSTRIDE_];
            float S1 = 0.f, S2 = 0.f;
            #pragma unroll
            for (int bb = 0; bb < NB_; bb++){ S1 += pst[bb][0]; S2 += pst[bb][1]; }
            float mu  = S1 * (1.f/MID_);
            float var = S2 * (1.f/MID_) - mu*mu;
            float inv = rsqrtf(var + LN_EPS_);
            float s = inv*(s1 - mu*Ac) + Bcc;
            float o = 1.f/(1.f + expf(-s));
            if ((wbits[(t<<3) + (tid>>5)] >> (tid&31)) & 1u)
                commonS[tid ^ (((tid>>5)&7)<<2)] = o;
        }
        __syncthreads();                 // bar5: commonS updated
    }
    if (role == 0 && tid < N_)
        commonFinal[tid] = commonS[tid ^ (((tid>>5)&7)<<2)];
}

__global__ void k_out(const float* __restrict__ commonFinal, float* __restrict__ out){
    int idx = blockIdx.x*blockDim.x + threadIdx.x;     // 524288
    out[idx] = commonFinal[idx & (N_-1)];
}

// ---------------- launch ----------------

extern "C" void kernel_launch(void* const* d_in, const int* in_sizes, int n_in,
                              void* d_out, int out_size, void* d_ws, size_t ws_size,
                              hipStream_t stream)
{
    const float* xs    = (const float*)d_in[0];
    const int*   ids   = (const int*)  d_in[1];
    const float* w1    = (const float*)d_in[2];
    const float* b1    = (const float*)d_in[3];
    const float* gamma = (const float*)d_in[4];
    const float* beta  = (const float*)d_in[5];
    const float* w2    = (const float*)d_in[6];
    const float* b2    = (const float*)d_in[7];
    float* out = (float*)d_out;

    float* ws      = (float*)d_ws;
    float* probs   = ws;                     // 524288 f32
    // slots alias probs[2048:] + w2T (both dead during k_fast):
    float* slots   = ws + 2048;              // 253*2304 = 582912 f32, ends 584960
    float* w2T     = ws + 524288;            // 131072 (used only before k_fast)
    float* A       = ws + 786432;            // 256
    float* Bc      = ws + 786688;            // 256
    float* ps      = ws + 786944;            // 2048
    float* newval  = ws + 788992;            // 256
    int*   wrote   = (int*)(ws + 789248);    // 256
    unsigned int* wmaskb = (unsigned int*)(ws + 805888);    // 2048 -> ends 807936
    int*   tagw32  = (int*)(ws + 807936);    // 253*16 u64 = 8096 ints -> ends 816032
    unsigned long long* tagw = (unsigned long long*)tagw32;
    int*   cnt     = tagw32 + NSTEP_*TAGST_*2;              // 8
    int*   winner  = cnt + 8;                               // 1
    float* commonFinal = ws + 816064;        // 256 -> ends 816320 (~3.27 MB)

    k_init<<<2048, 256, 0, stream>>>(xs, w2, probs, w2T, wmaskb, tagw32,
                                     cnt, winner);
    k_maskb<<<2048, 256, 0, stream>>>(ids, wmaskb);
    k_ab<<<256, 256, 0, stream>>>(gamma, beta, w2, b2, A, Bc);

    for (int t = 0; t < 3; t++){
        k_full_rows<<<256, 256, 0, stream>>>(probs, w1, b1, gamma, beta, w2T, b2,
                                             ids, ps, t);
        k_scatter<<<1, 256, 0, stream>>>(ids, ps, newval, wrote, t);
        if (t < 2) k_apply<<<2048, 256, 0, stream>>>(probs, newval, wrote);
    }

    k_fast<<<NBLK_, 512, 0, stream>>>(w1, b1, gamma, w2, A, Bc, wmaskb, probs,
                                      newval, wrote, slots, tagw, cnt, winner,
                                      commonFinal, 3);
    k_out<<<2048, 256, 0, stream>>>(commonFinal, out);
}

// Round 13
// 674.987 us; speedup vs baseline: 1.1600x; 1.0715x over previous
//
#include <hip/hip_runtime.h>
#include <math.h>

#define S_ 2048
#define N_ 256
#define MID_ 512
#define NB_ 8
#define JSL_ 64   // MID_/NB_
#define LN_EPS_ 1e-5f
#define NBLK_ 64          // blocks launched for the election
#define NSTEP_ 253        // fast-path steps (t = 3..255)
#define BSTRIDE_ 288      // floats per role payload (256 + 2 stats + pad; 9 x 128B lines)
#define SLOT_F_ (NB_*BSTRIDE_)   // 2304 floats per step slot
#define TAGST_ 16         // u64 per step tag line (128 B each)
#define TAG_TARGET_ 0x0101010101010101ULL

typedef float f32x4 __attribute__((ext_vector_type(4)));
typedef float f32x2 __attribute__((ext_vector_type(2)));

__device__ __forceinline__ float gelu_exact(float x){
    return 0.5f * x * (1.0f + erff(x * 0.70710678118654752440f));
}

// ---------------- setup kernels ----------------

__global__ void k_init(unsigned int* __restrict__ wmaskb, int* __restrict__ tagw32,
                       int* __restrict__ cnt, int* __restrict__ winner)
{
    int idx = blockIdx.x * blockDim.x + threadIdx.x;   // 64 blocks x 256 = 16384
    if (idx < (N_*N_)/32) wmaskb[idx] = 0u;
    if (idx < NSTEP_*TAGST_*2) tagw32[idx] = 0;        // tag words (as ints)
    if (idx < 8) cnt[idx] = 0;
    if (idx == 0) *winner = -1;
}

// winners[t][c] = last k with ids[k,t]==c (numpy last-wins), else -1; t=0..2
__global__ void k_prep(const int* __restrict__ ids, int* __restrict__ winners){
    __shared__ int lastk[3][N_];
    int tid = threadIdx.x;
    lastk[0][tid] = -1; lastk[1][tid] = -1; lastk[2][tid] = -1;
    __syncthreads();
    for (int k = tid; k < S_; k += 256){
        atomicMax(&lastk[0][ids[k*N_ + 0]], k);
        atomicMax(&lastk[1][ids[k*N_ + 1]], k);
        atomicMax(&lastk[2][ids[k*N_ + 2]], k);
    }
    __syncthreads();
    winners[0*N_ + tid] = lastk[0][tid];
    winners[1*N_ + tid] = lastk[1][tid];
    winners[2*N_ + tid] = lastk[2][tid];
}

// build bit-mask directly: wmaskb[t*8 + c/32] |= 1<<(c%32)
__global__ void k_maskb(const int* __restrict__ ids, unsigned int* __restrict__ wmaskb){
    int i = blockIdx.x*blockDim.x + threadIdx.x;       // 524288 = S_*N_
    if (i < S_*N_){
        int t = i & (N_-1);        // i = k*256 + t  (row-major ids_ary[k][t])
        int c = ids[i];
        atomicOr(&wmaskb[(t<<3) + (c>>5)], 1u << (c&31));
    }
}

__global__ void k_ab(const float* __restrict__ gamma, const float* __restrict__ beta,
                     const float* __restrict__ w2, const float* __restrict__ b2,
                     float* __restrict__ A, float* __restrict__ Bc){
    __shared__ float ra[256], rb[256];
    int c = blockIdx.x, tid = threadIdx.x;
    float a = 0.f, b = 0.f;
    for (int j = tid; j < MID_; j += 256){
        float v = w2[j*N_ + c];
        a += gamma[j]*v;
        b += beta[j]*v;
    }
    ra[tid] = a; rb[tid] = b; __syncthreads();
    for (int off = 128; off > 0; off >>= 1){
        if (tid < off){ ra[tid] += ra[tid+off]; rb[tid] += rb[tid+off]; }
        __syncthreads();
    }
    if (tid == 0){ A[c] = ra[0]; Bc[c] = rb[0] + b2[c]; }
}

// ---------------- winner-only exact step (t = 0..2) ----------------
// Only winner rows matter: probs[:, ids]=ps broadcasts row lastk[c]'s value to
// column c for ALL rows. Each winner row produces exactly ONE output column.
// 64 blocks x 4 columns; one wave per (column, winner-row). Input row built
// from the overlay cascade (xs -> nv0 if w0 -> nv1 if w1); no probs array.

__global__ __launch_bounds__(256) void k_fullW(
    const float* __restrict__ xs, const float* __restrict__ w1,
    const float* __restrict__ b1, const float* __restrict__ gamma,
    const float* __restrict__ beta, const float* __restrict__ w2,
    const float* __restrict__ b2, const int* __restrict__ winners,
    float* __restrict__ nv, int t)
{
    __shared__ float prow[4][N_];
    int tid = threadIdx.x;
    int r = tid >> 6, l = tid & 63;
    int c = blockIdx.x*4 + r;
    int kr = winners[t*N_ + c];
    int krow = kr < 0 ? 0 : kr;          // safe index; result unused if kr<0
    #pragma unroll
    for (int q = 0; q < 4; q++){
        int cc = l*4 + q;
        float v = xs[krow*N_ + cc];
        if (t > 0 && winners[cc] >= 0)      v = nv[cc];
        if (t > 1 && winners[N_ + cc] >= 0) v = nv[N_ + cc];
        prow[r][cc] = v;
    }
    // prow[r] is wave-private (written and read by wave r only)
    float h[8];
    #pragma unroll
    for (int m = 0; m < 8; m++) h[m] = b1[l + 64*m];
    for (int cc = 0; cc < N_; cc++){
        float p = prow[r][cc];
        const float* w1r = w1 + cc*MID_;
        #pragma unroll
        for (int m = 0; m < 8; m++) h[m] = fmaf(p, w1r[l + 64*m], h[m]);
    }
    float s1 = 0.f, s2 = 0.f;
    #pragma unroll
    for (int m = 0; m < 8; m++){
        float g = gelu_exact(h[m]);
        h[m] = g; s1 += g; s2 += g*g;
    }
    #pragma unroll
    for (int off = 32; off > 0; off >>= 1){
        s1 += __shfl_xor(s1, off, 64);
        s2 += __shfl_xor(s2, off, 64);
    }
    float mu  = s1 * (1.f/MID_);
    float var = s2 * (1.f/MID_) - mu*mu;
    float inv = rsqrtf(var + LN_EPS_);
    float acc = 0.f;
    #pragma unroll
    for (int m = 0; m < 8; m++){
        int j = l + 64*m;
        float hn = (h[m] - mu)*inv*gamma[j] + beta[j];
        acc = fmaf(hn, w2[j*N_ + c], acc);
    }
    #pragma unroll
    for (int off = 32; off > 0; off >>= 1) acc += __shfl_xor(acc, off, 64);
    if (l == 0) nv[t*N_ + c] = 1.f/(1.f + expf(-(acc + b2[c])));
}

// ---------------- persistent single-row fast path (t = 3..255) ----------------
// r12-proven structure: same-XCD team of 8 (RMW election), register weights,
// never-reused slots, block drain before publish, fair-atomic u64 tag word.
// Trims: 8 pollers hot-poll + import own stats pair (merges two barriers);
// no s_sleep; init = 3-level winner cascade (== r12's wrote?newval:probs).

__global__ __launch_bounds__(512) void k_fast(
    const float* __restrict__ w1, const float* __restrict__ b1,
    const float* __restrict__ gamma, const float* __restrict__ w2,
    const float* __restrict__ A, const float* __restrict__ Bc,
    const unsigned int* __restrict__ wmaskb, const float* __restrict__ xs,
    const int* __restrict__ winners3, const float* __restrict__ nv,
    float* __restrict__ slots, unsigned long long* __restrict__ tagw,
    int* __restrict__ cnt, int* __restrict__ winner,
    float* __restrict__ commonFinal, int t0)
{
    __shared__ int s_role;
    __shared__ __attribute__((aligned(16))) float commonS[N_];  // col-swizzled
    __shared__ __attribute__((aligned(16))) float gvals[JSL_];
    __shared__ float ws8[16];            // per-wave LN-stat partials
    __shared__ float pst[NB_][2];        // imported stats
    __shared__ unsigned int wbits[(N_*N_)/32];  // 8 KiB bit-mask

    int tid = threadIdx.x;

    // ---- election: RMW-only, hang-proof (r5/r9/r10/r12-proven) ----
    if (tid == 0){
        int xcd;
        asm volatile("s_getreg_b32 %0, hwreg(HW_REG_XCC_ID)" : "=s"(xcd));
        xcd &= 7;
        int pos = atomicAdd(&cnt[xcd], 1);
        int role = -1;
        if (pos == NB_ - 1){                       // 8th block on this XCD
            int old = atomicCAS(winner, -1, xcd);
            if (old == -1) role = NB_ - 1;
        } else if (pos < NB_ - 1){
            int w;
            while ((w = atomicCAS(winner, -2, -2)) == -1)
                __builtin_amdgcn_s_sleep(2);
            if (w == xcd) role = pos;
        }
        s_role = role;
    }
    __syncthreads();
    int role = s_role;
    if (role < 0) return;
    int j0 = role * JSL_;

    int l = tid & 63, w = tid >> 6;
    int cg = l & 7;                      // Phase A c-group: c in [cg*32, cg*32+32)
    int jA = (w<<3) + (l>>3);            // Phase A block-local j in [0,64)
    int cB = w*32 + (l & 31);            // Phase B output column
    int khalf = l >> 5;                  // Phase B k-half (0/1)

    // ---- stage weights into REGISTERS (statically indexed, fully unrolled) ----
    float w1r[32];
    #pragma unroll
    for (int cc = 0; cc < 32; cc++)
        w1r[cc] = w1[(cg*32 + cc)*MID_ + j0 + jA];
    float g2r[32];
    #pragma unroll
    for (int kk = 0; kk < 32; kk++)
        g2r[kk] = gamma[j0 + khalf*32 + kk] * w2[(j0 + khalf*32 + kk)*N_ + cB];
    float b1v = b1[j0 + jA];

    for (int i = tid; i < (N_*N_)/32; i += 512) wbits[i] = wmaskb[i];
    if (tid < N_){                       // overlay cascade (all rows identical by t0)
        float v = xs[tid];
        if (winners3[tid] >= 0)        v = nv[tid];
        if (winners3[N_ + tid] >= 0)   v = nv[N_ + tid];
        if (winners3[2*N_ + tid] >= 0) v = nv[2*N_ + tid];
        commonS[tid ^ (((tid>>5)&7)<<2)] = v;
    }
    float Ac  = (tid < N_) ? A[tid]  : 0.f;
    float Bcc = (tid < N_) ? Bc[tid] : 0.f;
    __syncthreads();

    for (int t = t0; t < N_; t++){
        int si = t - t0;
        float* slot = slots + si*SLOT_F_;          // fresh slot every step
        float* myp  = slot + role*BSTRIDE_;
        // Phase A (all 8 waves): h partials from register w1 + broadcast commonS
        {
            float a0=0.f, a1=0.f, a2=0.f, a3=0.f;
            #pragma unroll
            for (int cc = 0; cc < 8; cc++){
                f32x4 cv = *(const f32x4*)(&commonS[(cg*32 + cc*4) ^ (cg<<2)]);
                a0 = fmaf(w1r[cc*4+0], cv.x, a0);
                a1 = fmaf(w1r[cc*4+1], cv.y, a1);
                a2 = fmaf(w1r[cc*4+2], cv.z, a2);
                a3 = fmaf(w1r[cc*4+3], cv.w, a3);
            }
            float hp = (a0+a1) + (a2+a3);
            hp += __shfl_xor(hp, 1);     // reduce over cg (lane bits 0-2)
            hp += __shfl_xor(hp, 2);
            hp += __shfl_xor(hp, 4);
            float g = gelu_exact(hp + b1v);
            float s1 = g, s2 = g*g;
            s1 += __shfl_xor(s1, 8);  s2 += __shfl_xor(s2, 8);   // over j (bits 3-5)
            s1 += __shfl_xor(s1, 16); s2 += __shfl_xor(s2, 16);
            s1 += __shfl_xor(s1, 32); s2 += __shfl_xor(s2, 32);
            if (l == 0){ ws8[w*2] = s1; ws8[w*2+1] = s2; }
            if (cg == 0) gvals[jA] = g;
        }
        __syncthreads();                 // bar1: gvals/ws8 ready
        // Phase B (all 8 waves): partial matvec from register gw2 + broadcast gvals
        {
            float p0=0.f, p1=0.f, p2=0.f, p3=0.f;
            #pragma unroll
            for (int kk = 0; kk < 8; kk++){
                f32x4 gv = *(const f32x4*)(&gvals[khalf*32 + kk*4]);
                p0 = fmaf(g2r[kk*4+0], gv.x, p0);
                p1 = fmaf(g2r[kk*4+1], gv.y, p1);
                p2 = fmaf(g2r[kk*4+2], gv.z, p2);
                p3 = fmaf(g2r[kk*4+3], gv.w, p3);
            }
            float p = (p0+p1) + (p2+p3);
            p += __shfl_xor(p, 32);      // combine the two k-halves
            if (l < 32) myp[cB] = p;     // coalesced 128B per wave
        }
        if (tid == 0){
            float S1 = 0.f, S2 = 0.f;
            #pragma unroll
            for (int ww = 0; ww < 8; ww++){ S1 += ws8[ww*2]; S2 += ws8[ww*2+1]; }
            f32x2 st; st.x = S1; st.y = S2;
            *(f32x2*)(myp + 256) = st;
        }
        asm volatile("s_waitcnt vmcnt(0)" ::: "memory");  // own stores acked at L2
        __syncthreads();                 // bar2: ALL payload stores at L2
        // publish (fair RMW) + 8 parallel hot polls + own-stats import
        {
            unsigned long long* tp = tagw + si*TAGST_;
            if (tid == 0) atomicAdd(tp, 1ULL << (8*role));
            if (tid < NB_){
                while (atomicAdd(tp, 0ULL) != TAG_TARGET_) {}
                f32x2 st = *(const f32x2*)(slot + tid*BSTRIDE_ + 256);
                pst[tid][0] = st.x; pst[tid][1] = st.y;
            }
        }
        __syncthreads();                 // bar3: all payloads at L2, stats in LDS
        // P4: payload first-touch reads, finish
        if (tid < N_){
            const float* sp = slot + tid;
            float s1 = 0.f;
            #pragma unroll
            for (int bb = 0; bb < NB_; bb++) s1 += sp[bb*BSTRIDE_];
            float S1 = 0.f, S2 = 0.f;
            #pragma unroll
            for (int bb = 0; bb < NB_; bb++){ S1 += pst[bb][0]; S2 += pst[bb][1]; }
            float mu  = S1 * (1.f/MID_);
            float var = S2 * (1.f/MID_) - mu*mu;
            float inv = rsqrtf(var + LN_EPS_);
            float s = inv*(s1 - mu*Ac) + Bcc;
            float o = 1.f/(1.f + expf(-s));
            if ((wbits[(t<<3) + (tid>>5)] >> (tid&31)) & 1u)
                commonS[tid ^ (((tid>>5)&7)<<2)] = o;
        }
        __syncthreads();                 // bar4: commonS updated
    }
    if (role == 0 && tid < N_)
        commonFinal[tid] = commonS[tid ^ (((tid>>5)&7)<<2)];
}

__global__ void k_out(const float* __restrict__ commonFinal, float* __restrict__ out){
    int idx = blockIdx.x*blockDim.x + threadIdx.x;     // 524288
    out[idx] = commonFinal[idx & (N_-1)];
}

// ---------------- launch ----------------

extern "C" void kernel_launch(void* const* d_in, const int* in_sizes, int n_in,
                              void* d_out, int out_size, void* d_ws, size_t ws_size,
                              hipStream_t stream)
{
    const float* xs    = (const float*)d_in[0];
    const int*   ids   = (const int*)  d_in[1];
    const float* w1    = (const float*)d_in[2];
    const float* b1    = (const float*)d_in[3];
    const float* gamma = (const float*)d_in[4];
    const float* beta  = (const float*)d_in[5];
    const float* w2    = (const float*)d_in[6];
    const float* b2    = (const float*)d_in[7];
    float* out = (float*)d_out;

    float* ws      = (float*)d_ws;
    float* slots   = ws;                       // 253*2304 = 582912 f32
    float* commonFinal = ws + 582912;          // 256
    float* nv      = ws + 583168;              // 3*256 = 768
    float* A       = ws + 583936;              // 256
    float* Bc      = ws + 584192;              // 256
    int*   winners = (int*)(ws + 584448);      // 3*256 = 768 ints
    unsigned int* wmaskb = (unsigned int*)(ws + 585216);  // 2048
    int*   tagw32  = (int*)(ws + 587264);      // 253*16*2 = 8096 ints
    unsigned long long* tagw = (unsigned long long*)tagw32;
    int*   cnt     = tagw32 + NSTEP_*TAGST_*2; // 8
    int*   winner  = cnt + 8;                  // 1 -> ends ~595373 f32 (~2.38 MB)

    k_init<<<64, 256, 0, stream>>>(wmaskb, tagw32, cnt, winner);
    k_prep<<<1, 256, 0, stream>>>(ids, winners);
    k_maskb<<<2048, 256, 0, stream>>>(ids, wmaskb);
    k_ab<<<256, 256, 0, stream>>>(gamma, beta, w2, b2, A, Bc);

    for (int t = 0; t < 3; t++)
        k_fullW<<<64, 256, 0, stream>>>(xs, w1, b1, gamma, beta, w2, b2,
                                        winners, nv, t);

    k_fast<<<NBLK_, 512, 0, stream>>>(w1, b1, gamma, w2, A, Bc, wmaskb, xs,
                                      winners, nv, slots, tagw, cnt, winner,
                                      commonFinal, 3);
    k_out<<<2048, 256, 0, stream>>>(commonFinal, out);
}

// Round 14
// 637.169 us; speedup vs baseline: 1.2289x; 1.0594x over previous
//
#include <hip/hip_runtime.h>
#include <math.h>

#define S_ 2048
#define N_ 256
#define MID_ 512
#define NB_ 8
#define JSL_ 64   // MID_/NB_
#define LN_EPS_ 1e-5f
#define NBLK_ 64          // blocks launched for the election
#define NSTEP_ 253        // fast-path steps (t = 3..255)
#define BSTRIDE_ 288      // floats per role payload (256 + 2 stats + pad; 9 x 128B lines)
#define SLOT_F_ (NB_*BSTRIDE_)   // 2304 floats per step slot
#define TAGST_ 16         // u64 per step tag line (128 B each)
#define TAG_TARGET_ 0x0101010101010101ULL

typedef float f32x4 __attribute__((ext_vector_type(4)));
typedef float f32x2 __attribute__((ext_vector_type(2)));

__device__ __forceinline__ float gelu_exact(float x){
    return 0.5f * x * (1.0f + erff(x * 0.70710678118654752440f));
}

// ---------------- consolidated setup (one kernel, 256 blocks) ----------------
// Block bi: (1) zeroes its 32-int stripe of the tag area; (2) builds
// wmaskb[bi] via LDS atomicOr (no global atomic storm); (3) if bi<3 also
// computes winners[bi][c] (last-k-wins) via LDS atomicMax from the SAME ids
// values; (4) computes A[bi], Bc[bi] (k_ab role). Block 0 zeroes cnt/winner.

__global__ __launch_bounds__(256) void k_setup(
    const int* __restrict__ ids, const float* __restrict__ gamma,
    const float* __restrict__ beta, const float* __restrict__ w2,
    const float* __restrict__ b2,
    unsigned int* __restrict__ wmaskb, int* __restrict__ winners,
    float* __restrict__ A, float* __restrict__ Bc,
    int* __restrict__ tagw32, int* __restrict__ cnt, int* __restrict__ winner)
{
    __shared__ float ra[256], rb[256];
    __shared__ unsigned int mb[8];
    __shared__ int lk[N_];
    int bi = blockIdx.x, tid = threadIdx.x;

    if (tid < 32){
        int ii = bi*32 + tid;
        if (ii < NSTEP_*TAGST_*2) tagw32[ii] = 0;
    }
    if (bi == 0 && tid < 8) cnt[tid] = 0;
    if (bi == 0 && tid == 0) *winner = -1;

    if (tid < 8) mb[tid] = 0u;
    lk[tid] = -1;
    __syncthreads();
    #pragma unroll
    for (int m = 0; m < 8; m++){
        int k = tid + m*256;
        int c = ids[k*N_ + bi];
        atomicOr(&mb[c>>5], 1u << (c&31));
        if (bi < 3) atomicMax(&lk[c], k);
    }
    // k_ab role: column c = bi
    float a = 0.f, b = 0.f;
    for (int j = tid; j < MID_; j += 256){
        float v = w2[j*N_ + bi];
        a += gamma[j]*v;
        b += beta[j]*v;
    }
    ra[tid] = a; rb[tid] = b;
    __syncthreads();
    for (int off = 128; off > 0; off >>= 1){
        if (tid < off){ ra[tid] += ra[tid+off]; rb[tid] += rb[tid+off]; }
        __syncthreads();
    }
    if (tid == 0){ A[bi] = ra[0]; Bc[bi] = rb[0] + b2[bi]; }
    if (tid < 8) wmaskb[bi*8 + tid] = mb[tid];
    if (bi < 3) winners[bi*N_ + tid] = lk[tid];
}

// ---------------- winner-only exact step (t = 0..2) ----------------
// Only winner rows matter: probs[:, ids]=ps broadcasts row lastk[c]'s value to
// column c for ALL rows. Each winner row produces exactly ONE output column.

__global__ __launch_bounds__(256) void k_fullW(
    const float* __restrict__ xs, const float* __restrict__ w1,
    const float* __restrict__ b1, const float* __restrict__ gamma,
    const float* __restrict__ beta, const float* __restrict__ w2,
    const float* __restrict__ b2, const int* __restrict__ winners,
    float* __restrict__ nv, int t)
{
    __shared__ float prow[4][N_];
    int tid = threadIdx.x;
    int r = tid >> 6, l = tid & 63;
    int c = blockIdx.x*4 + r;
    int kr = winners[t*N_ + c];
    int krow = kr < 0 ? 0 : kr;          // safe index; result unused if kr<0
    #pragma unroll
    for (int q = 0; q < 4; q++){
        int cc = l*4 + q;
        float v = xs[krow*N_ + cc];
        if (t > 0 && winners[cc] >= 0)      v = nv[cc];
        if (t > 1 && winners[N_ + cc] >= 0) v = nv[N_ + cc];
        prow[r][cc] = v;
    }
    // prow[r] is wave-private (written and read by wave r only)
    float h[8];
    #pragma unroll
    for (int m = 0; m < 8; m++) h[m] = b1[l + 64*m];
    for (int cc = 0; cc < N_; cc++){
        float p = prow[r][cc];
        const float* w1r = w1 + cc*MID_;
        #pragma unroll
        for (int m = 0; m < 8; m++) h[m] = fmaf(p, w1r[l + 64*m], h[m]);
    }
    float s1 = 0.f, s2 = 0.f;
    #pragma unroll
    for (int m = 0; m < 8; m++){
        float g = gelu_exact(h[m]);
        h[m] = g; s1 += g; s2 += g*g;
    }
    #pragma unroll
    for (int off = 32; off > 0; off >>= 1){
        s1 += __shfl_xor(s1, off, 64);
        s2 += __shfl_xor(s2, off, 64);
    }
    float mu  = s1 * (1.f/MID_);
    float var = s2 * (1.f/MID_) - mu*mu;
    float inv = rsqrtf(var + LN_EPS_);
    float acc = 0.f;
    #pragma unroll
    for (int m = 0; m < 8; m++){
        int j = l + 64*m;
        float hn = (h[m] - mu)*inv*gamma[j] + beta[j];
        acc = fmaf(hn, w2[j*N_ + c], acc);
    }
    #pragma unroll
    for (int off = 32; off > 0; off >>= 1) acc += __shfl_xor(acc, off, 64);
    if (l == 0) nv[t*N_ + c] = 1.f/(1.f + expf(-(acc + b2[c])));
}

// ---------------- persistent single-row fast path (t = 3..255) ----------------
// r13-proven loop, byte-identical. Added epilogue: the 8 team blocks write
// the 2048x256 output directly (256 rows each, coalesced f32x4 broadcast).

__global__ __launch_bounds__(512) void k_fast(
    const float* __restrict__ w1, const float* __restrict__ b1,
    const float* __restrict__ gamma, const float* __restrict__ w2,
    const float* __restrict__ A, const float* __restrict__ Bc,
    const unsigned int* __restrict__ wmaskb, const float* __restrict__ xs,
    const int* __restrict__ winners3, const float* __restrict__ nv,
    float* __restrict__ slots, unsigned long long* __restrict__ tagw,
    int* __restrict__ cnt, int* __restrict__ winner,
    float* __restrict__ out, int t0)
{
    __shared__ int s_role;
    __shared__ __attribute__((aligned(16))) float commonS[N_];  // col-swizzled
    __shared__ __attribute__((aligned(16))) float gvals[JSL_];
    __shared__ __attribute__((aligned(16))) float crow[N_];
    __shared__ float ws8[16];            // per-wave LN-stat partials
    __shared__ float pst[NB_][2];        // imported stats
    __shared__ unsigned int wbits[(N_*N_)/32];  // 8 KiB bit-mask

    int tid = threadIdx.x;

    // ---- election: RMW-only, hang-proof (r5..r13-proven) ----
    if (tid == 0){
        int xcd;
        asm volatile("s_getreg_b32 %0, hwreg(HW_REG_XCC_ID)" : "=s"(xcd));
        xcd &= 7;
        int pos = atomicAdd(&cnt[xcd], 1);
        int role = -1;
        if (pos == NB_ - 1){                       // 8th block on this XCD
            int old = atomicCAS(winner, -1, xcd);
            if (old == -1) role = NB_ - 1;
        } else if (pos < NB_ - 1){
            int w;
            while ((w = atomicCAS(winner, -2, -2)) == -1)
                __builtin_amdgcn_s_sleep(2);
            if (w == xcd) role = pos;
        }
        s_role = role;
    }
    __syncthreads();
    int role = s_role;
    if (role < 0) return;
    int j0 = role * JSL_;

    int l = tid & 63, w = tid >> 6;
    int cg = l & 7;                      // Phase A c-group: c in [cg*32, cg*32+32)
    int jA = (w<<3) + (l>>3);            // Phase A block-local j in [0,64)
    int cB = w*32 + (l & 31);            // Phase B output column
    int khalf = l >> 5;                  // Phase B k-half (0/1)

    // ---- stage weights into REGISTERS (statically indexed, fully unrolled) ----
    float w1r[32];
    #pragma unroll
    for (int cc = 0; cc < 32; cc++)
        w1r[cc] = w1[(cg*32 + cc)*MID_ + j0 + jA];
    float g2r[32];
    #pragma unroll
    for (int kk = 0; kk < 32; kk++)
        g2r[kk] = gamma[j0 + khalf*32 + kk] * w2[(j0 + khalf*32 + kk)*N_ + cB];
    float b1v = b1[j0 + jA];

    for (int i = tid; i < (N_*N_)/32; i += 512) wbits[i] = wmaskb[i];
    if (tid < N_){                       // overlay cascade (all rows identical by t0)
        float v = xs[tid];
        if (winners3[tid] >= 0)        v = nv[tid];
        if (winners3[N_ + tid] >= 0)   v = nv[N_ + tid];
        if (winners3[2*N_ + tid] >= 0) v = nv[2*N_ + tid];
        commonS[tid ^ (((tid>>5)&7)<<2)] = v;
    }
    float Ac  = (tid < N_) ? A[tid]  : 0.f;
    float Bcc = (tid < N_) ? Bc[tid] : 0.f;
    __syncthreads();

    for (int t = t0; t < N_; t++){
        int si = t - t0;
        float* slot = slots + si*SLOT_F_;          // fresh slot every step
        float* myp  = slot + role*BSTRIDE_;
        // Phase A (all 8 waves): h partials from register w1 + broadcast commonS
        {
            float a0=0.f, a1=0.f, a2=0.f, a3=0.f;
            #pragma unroll
            for (int cc = 0; cc < 8; cc++){
                f32x4 cv = *(const f32x4*)(&commonS[(cg*32 + cc*4) ^ (cg<<2)]);
                a0 = fmaf(w1r[cc*4+0], cv.x, a0);
                a1 = fmaf(w1r[cc*4+1], cv.y, a1);
                a2 = fmaf(w1r[cc*4+2], cv.z, a2);
                a3 = fmaf(w1r[cc*4+3], cv.w, a3);
            }
            float hp = (a0+a1) + (a2+a3);
            hp += __shfl_xor(hp, 1);     // reduce over cg (lane bits 0-2)
            hp += __shfl_xor(hp, 2);
            hp += __shfl_xor(hp, 4);
            float g = gelu_exact(hp + b1v);
            float s1 = g, s2 = g*g;
            s1 += __shfl_xor(s1, 8);  s2 += __shfl_xor(s2, 8);   // over j (bits 3-5)
            s1 += __shfl_xor(s1, 16); s2 += __shfl_xor(s2, 16);
            s1 += __shfl_xor(s1, 32); s2 += __shfl_xor(s2, 32);
            if (l == 0){ ws8[w*2] = s1; ws8[w*2+1] = s2; }
            if (cg == 0) gvals[jA] = g;
        }
        __syncthreads();                 // bar1: gvals/ws8 ready
        // Phase B (all 8 waves): partial matvec from register gw2 + broadcast gvals
        {
            float p0=0.f, p1=0.f, p2=0.f, p3=0.f;
            #pragma unroll
            for (int kk = 0; kk < 8; kk++){
                f32x4 gv = *(const f32x4*)(&gvals[khalf*32 + kk*4]);
                p0 = fmaf(g2r[kk*4+0], gv.x, p0);
                p1 = fmaf(g2r[kk*4+1], gv.y, p1);
                p2 = fmaf(g2r[kk*4+2], gv.z, p2);
                p3 = fmaf(g2r[kk*4+3], gv.w, p3);
            }
            float p = (p0+p1) + (p2+p3);
            p += __shfl_xor(p, 32);      // combine the two k-halves
            if (l < 32) myp[cB] = p;     // coalesced 128B per wave
        }
        if (tid == 0){
            float S1 = 0.f, S2 = 0.f;
            #pragma unroll
            for (int ww = 0; ww < 8; ww++){ S1 += ws8[ww*2]; S2 += ws8[ww*2+1]; }
            f32x2 st; st.x = S1; st.y = S2;
            *(f32x2*)(myp + 256) = st;
        }
        asm volatile("s_waitcnt vmcnt(0)" ::: "memory");  // own stores acked at L2
        __syncthreads();                 // bar2: ALL payload stores at L2
        // publish (fair RMW) + 8 parallel hot polls + own-stats import
        {
            unsigned long long* tp = tagw + si*TAGST_;
            if (tid == 0) atomicAdd(tp, 1ULL << (8*role));
            if (tid < NB_){
                while (atomicAdd(tp, 0ULL) != TAG_TARGET_) {}
                f32x2 st = *(const f32x2*)(slot + tid*BSTRIDE_ + 256);
                pst[tid][0] = st.x; pst[tid][1] = st.y;
            }
        }
        __syncthreads();                 // bar3: all payloads at L2, stats in LDS
        // P4: payload first-touch reads, finish
        if (tid < N_){
            const float* sp = slot + tid;
            float s1 = 0.f;
            #pragma unroll
            for (int bb = 0; bb < NB_; bb++) s1 += sp[bb*BSTRIDE_];
            float S1 = 0.f, S2 = 0.f;
            #pragma unroll
            for (int bb = 0; bb < NB_; bb++){ S1 += pst[bb][0]; S2 += pst[bb][1]; }
            float mu  = S1 * (1.f/MID_);
            float var = S2 * (1.f/MID_) - mu*mu;
            float inv = rsqrtf(var + LN_EPS_);
            float s = inv*(s1 - mu*Ac) + Bcc;
            float o = 1.f/(1.f + expf(-s));
            if ((wbits[(t<<3) + (tid>>5)] >> (tid&31)) & 1u)
                commonS[tid ^ (((tid>>5)&7)<<2)] = o;
        }
        __syncthreads();                 // bar4: commonS updated
    }
    // ---- epilogue: broadcast-write this block's 256-row output slice ----
    if (tid < N_) crow[tid] = commonS[tid ^ (((tid>>5)&7)<<2)];
    __syncthreads();
    {
        float* obase = out + (role*256)*N_;        // rows [role*256, +256)
        for (int i = tid; i < 256*(N_/4); i += 512){
            int rr = i >> 6, v4 = i & 63;
            *(f32x4*)(&obase[rr*N_ + v4*4]) = *(const f32x4*)(&crow[v4*4]);
        }
    }
}

// ---------------- launch ----------------

extern "C" void kernel_launch(void* const* d_in, const int* in_sizes, int n_in,
                              void* d_out, int out_size, void* d_ws, size_t ws_size,
                              hipStream_t stream)
{
    const float* xs    = (const float*)d_in[0];
    const int*   ids   = (const int*)  d_in[1];
    const float* w1    = (const float*)d_in[2];
    const float* b1    = (const float*)d_in[3];
    const float* gamma = (const float*)d_in[4];
    const float* beta  = (const float*)d_in[5];
    const float* w2    = (const float*)d_in[6];
    const float* b2    = (const float*)d_in[7];
    float* out = (float*)d_out;

    float* ws      = (float*)d_ws;
    float* slots   = ws;                       // 253*2304 = 582912 f32
    float* nv      = ws + 582912;              // 3*256 = 768
    float* A       = ws + 583680;              // 256
    float* Bc      = ws + 583936;              // 256
    int*   winners = (int*)(ws + 584192);      // 3*256 = 768 ints
    unsigned int* wmaskb = (unsigned int*)(ws + 584960);  // 2048
    int*   tagw32  = (int*)(ws + 587008);      // 253*16*2 = 8096 ints (8B-aligned)
    unsigned long long* tagw = (unsigned long long*)tagw32;
    int*   cnt     = tagw32 + NSTEP_*TAGST_*2; // 8
    int*   winner  = cnt + 8;                  // 1 -> ends ~595113 f32 (~2.38 MB)

    k_setup<<<256, 256, 0, stream>>>(ids, gamma, beta, w2, b2, wmaskb, winners,
                                     A, Bc, tagw32, cnt, winner);

    for (int t = 0; t < 3; t++)
        k_fullW<<<64, 256, 0, stream>>>(xs, w1, b1, gamma, beta, w2, b2,
                                        winners, nv, t);

    k_fast<<<NBLK_, 512, 0, stream>>>(w1, b1, gamma, w2, A, Bc, wmaskb, xs,
                                      winners, nv, slots, tagw, cnt, winner,
                                      out, 3);
}